// Round 1
// 20240.889 us; speedup vs baseline: 2.0425x; 2.0425x over previous
//
#include <hip/hip_runtime.h>
#include <hip/hip_bf16.h>
#include <stdint.h>

#define SEQ   512
#define BATCH 128
#define DIM   1024
#define BD    (BATCH * DIM)
#define NBLK  256
#define LDS_BYTES 131072

typedef __bf16 bf16x8 __attribute__((ext_vector_type(8)));
typedef float  f32x4  __attribute__((ext_vector_type(4)));

__device__ __forceinline__ float sigf(float x) { return 1.0f / (1.0f + __expf(-x)); }

__device__ __forceinline__ bf16x8 pack_f32(float4 a, float4 b) {
    bf16x8 r;
    r[0] = (__bf16)a.x; r[1] = (__bf16)a.y; r[2] = (__bf16)a.z; r[3] = (__bf16)a.w;
    r[4] = (__bf16)b.x; r[5] = (__bf16)b.y; r[6] = (__bf16)b.z; r[7] = (__bf16)b.w;
    return r;
}
__device__ __forceinline__ bf16x8 pack_u64(unsigned long long a, unsigned long long b) {
    uint4 u = make_uint4((unsigned)a, (unsigned)(a >> 32), (unsigned)b, (unsigned)(b >> 32));
    return __builtin_bit_cast(bf16x8, u);
}
// Device-scope (cross-XCD coherent) 8B load / 2B store: per-XCD L2 is not
// coherent, so all cross-block h-state goes through agent-scope atomics.
__device__ __forceinline__ unsigned long long ld_dev_u64(const __hip_bfloat16* p) {
    return __hip_atomic_load((const unsigned long long*)p, __ATOMIC_RELAXED,
                             __HIP_MEMORY_SCOPE_AGENT);
}
__device__ __forceinline__ void st_dev_bf16(__hip_bfloat16* p, float v) {
    unsigned short u = __builtin_bit_cast(unsigned short, (__bf16)v);
    __hip_atomic_store((unsigned short*)p, u, __ATOMIC_RELAXED, __HIP_MEMORY_SCOPE_AGENT);
}

// Grid barrier: counter at sc[0], generation at sc[64] (separate lines).
// All cross-block data moves via agent-scope atomics, so no cache-maintenance
// fence is needed here (a full __threadfence would invalidate L2 and kill
// emb/x residency). __syncthreads' vmcnt drain retires the atomic stores.
__device__ __forceinline__ void gsync(unsigned* sc) {
    __syncthreads();
    if (threadIdx.x == 0) {
        unsigned g = __hip_atomic_load(sc + 64, __ATOMIC_RELAXED, __HIP_MEMORY_SCOPE_AGENT);
        unsigned a = __hip_atomic_fetch_add(sc, 1u, __ATOMIC_ACQ_REL, __HIP_MEMORY_SCOPE_AGENT);
        if (a == NBLK - 1) {
            __hip_atomic_store(sc, 0u, __ATOMIC_RELAXED, __HIP_MEMORY_SCOPE_AGENT);
            __hip_atomic_store(sc + 64, g + 1u, __ATOMIC_RELEASE, __HIP_MEMORY_SCOPE_AGENT);
        } else {
            while (__hip_atomic_load(sc + 64, __ATOMIC_ACQUIRE, __HIP_MEMORY_SCOPE_AGENT) == g)
                __builtin_amdgcn_s_sleep(2);
        }
    }
    __syncthreads();
}

// One GEMM pair: gates_partial = A1 @ Ws0^T (s=0 waves) + A2 @ Ws1^T (s=1 waves),
// K tiled in 8 chunks of 128, A staged to LDS (XOR-swizzled, double-buffered),
// B fragments in registers (breg). Partials land in LDS part[8][32][64].
// LDS map: [0,64K) partials / weight-staging; [64K,96K) bufA[2]; [96K,128K) bufB[2].
template<bool GATHER>
__device__ __forceinline__ void run_gemm(
    const void* srcA, const __hip_bfloat16* srcB,
    const bf16x8 (&breg)[2][8], char* lds,
    int tid, int w, int s, int kq, int quad, int l16, int eb0, int exr)
{
    float* part = (float*)lds;
    char* bufA = lds + 65536;
    char* bufB = lds + 98304;

    f32x4 acc[4][2];
#pragma unroll
    for (int mt = 0; mt < 4; ++mt) {
        acc[mt][0] = (f32x4)(0.0f);
        acc[mt][1] = (f32x4)(0.0f);
    }

    unsigned long long sa[4], sb[4];
    float4 ga[4];

    // Issue chunk-kc loads early (values consumed later -> latency hidden).
    auto issue = [&](int kc) {
#pragma unroll
        for (int rep = 0; rep < 2; ++rep) {
            int colk = kc * 128 + (((eb0 + rep) ^ exr) << 3);   // pre-swizzled source col
            if constexpr (GATHER) {
                const float* p = (const float*)srcA + colk;
                ga[rep * 2 + 0] = *(const float4*)(p);
                ga[rep * 2 + 1] = *(const float4*)(p + 4);
            } else {
                const __hip_bfloat16* p = (const __hip_bfloat16*)srcA + colk;
                sa[rep * 2 + 0] = ld_dev_u64(p);
                sa[rep * 2 + 1] = ld_dev_u64(p + 4);
            }
            const __hip_bfloat16* q = srcB + colk;
            sb[rep * 2 + 0] = ld_dev_u64(q);
            sb[rep * 2 + 1] = ld_dev_u64(q + 4);
        }
    };
    auto wr = [&](int kc) {
        char* dA = bufA + (kc & 1) * 16384 + tid * 32;
        char* dB = bufB + (kc & 1) * 16384 + tid * 32;
#pragma unroll
        for (int rep = 0; rep < 2; ++rep) {
            bf16x8 va;
            if constexpr (GATHER) va = pack_f32(ga[rep * 2], ga[rep * 2 + 1]);
            else                  va = pack_u64(sa[rep * 2], sa[rep * 2 + 1]);
            *(bf16x8*)(dA + rep * 16) = va;
            *(bf16x8*)(dB + rep * 16) = pack_u64(sb[rep * 2], sb[rep * 2 + 1]);
        }
    };

    // A-frag base: row = mt*16+l16 (stride 256B), block = (kq*4+quad)^(row&7)
    const char* abase0 = (s ? bufB : bufA) + l16 * 256 + ((((kq * 4) + quad) ^ (l16 & 7)) * 16);

    issue(0); wr(0);
#pragma unroll
    for (int kc = 0; kc < 8; ++kc) {
        __syncthreads();                 // all wr(kc) visible; frees buf[(kc+1)&1]
        if (kc < 7) issue(kc + 1);
        {
            const char* ab = abase0 + (kc & 1) * 16384;
#pragma unroll
            for (int mt = 0; mt < 4; ++mt) {
                bf16x8 af = *(const bf16x8*)(ab + mt * 4096);
                acc[mt][0] = __builtin_amdgcn_mfma_f32_16x16x32_bf16(af, breg[0][kc], acc[mt][0], 0, 0, 0);
                acc[mt][1] = __builtin_amdgcn_mfma_f32_16x16x32_bf16(af, breg[1][kc], acc[mt][1], 0, 0, 0);
            }
        }
        if (kc < 7) wr(kc + 1);
    }

    // Partials: part[w][n][m] (dword idx), XOR-swizzled to spread banks.
#pragma unroll
    for (int mt = 0; mt < 4; ++mt)
#pragma unroll
        for (int nt = 0; nt < 2; ++nt) {
            int n  = nt * 16 + l16;
            int dw = (w * 2048 + n * 64 + mt * 16 + quad * 4) ^ ((n & 7) << 2);
            *(f32x4*)(part + dw) = acc[mt][nt];
        }
    __syncthreads();
}

__global__ __launch_bounds__(512, 2) void lstm_persist(
    const int* __restrict__ x, const float* __restrict__ emb,
    const float* __restrict__ Wih, const float* __restrict__ Whh,
    const float* __restrict__ bih, const float* __restrict__ bhh,
    const float* __restrict__ h0, const float* __restrict__ c0,
    const float* __restrict__ h02, const float* __restrict__ c02,
    __hip_bfloat16* __restrict__ hbase, unsigned* __restrict__ sync,
    float* __restrict__ out)
{
    extern __shared__ char lds[];

    const int tid  = threadIdx.x;
    const int w    = tid >> 6;
    const int lane = tid & 63;
    const int quad = lane >> 4;
    const int l16  = lane & 15;
    const int s    = w & 1;          // 0: Wih-product, 1: Whh-product
    const int kq   = w >> 1;         // K-quarter
    const int jg   = blockIdx.x >> 1;        // 128 column groups of 8
    const int mh   = blockIdx.x & 1;         // M half
    const int mbase = mh * 64;
    const int erow = tid >> 3;               // staging/epilogue local row
    const int eb0  = (tid & 7) * 2;          // staging block base
    const int exr  = erow & 7;               // staging swizzle
    const int col  = jg * 8 + (tid & 7);     // epilogue hidden col
    const int brow = mbase + erow;           // epilogue batch row
    const size_t off = (size_t)brow * DIM + col;

    __hip_bfloat16* hbf0  = hbase;
    __hip_bfloat16* hbf1  = hbase + BD;
    __hip_bfloat16* h1bf0 = hbase + 2 * BD;
    __hip_bfloat16* h1bf1 = hbase + 3 * BD;
    __hip_bfloat16* h2bf0 = hbase + 4 * BD;
    __hip_bfloat16* h2bf1 = hbase + 5 * BD;

    // ---- prologue: weights f32 -> LDS bf16 -> persistent register fragments ----
    // packed row n = j*4+g  <->  W row g*DIM + jg*8 + j  (gate-interleaved so the
    // epilogue's 4 gates are n = j*4 .. j*4+3)
    bf16x8 breg[2][8];
    for (int sm = 0; sm < 2; ++sm) {
        const float* wsrc = sm ? Whh : Wih;
        {
            int n  = tid >> 4;
            int cb = (tid & 15) * 64;
            size_t grow = (size_t)((n & 3) * DIM + jg * 8 + (n >> 2));
            const float* srcp = wsrc + grow * DIM + cb;
            char* dst = lds + n * 2048 + cb * 2;
#pragma unroll
            for (int cc = 0; cc < 8; ++cc) {
                float4 a = *(const float4*)(srcp + cc * 8);
                float4 b = *(const float4*)(srcp + cc * 8 + 4);
                *(bf16x8*)(dst + cc * 16) = pack_f32(a, b);
            }
        }
        __syncthreads();
        if (s == sm) {
#pragma unroll
            for (int nt = 0; nt < 2; ++nt)
#pragma unroll
                for (int kc = 0; kc < 8; ++kc)
                    breg[nt][kc] = *(const bf16x8*)(lds + (nt * 16 + l16) * 2048 +
                                                    kc * 256 + kq * 64 + quad * 16);
        }
        __syncthreads();
    }

    // ---- per-thread persistent state (one (row,col) cell per thread) ----
    float hc  = h0[col],  cc1 = c0[col];     // layer1 h(t-1), c(t-1)
    float hp  = hc,       cp  = cc1;         // layer1 h(t-2), c(t-2) (pad fallback for cell2)
    float h2f = h02[col], c2f = c02[col];    // layer2 state
    float bias[4];
#pragma unroll
    for (int g = 0; g < 4; ++g) bias[g] = bih[g * DIM + col] + bhh[g * DIM + col];

    // init broadcast buffers (parity 1 = "state before step 0")
    st_dev_bf16(hbf1 + off, hc);
    st_dev_bf16(h2bf1 + off, h2f);

    gsync(sync);

    float* part = (float*)lds;

    // phase t: cell2(t-1) then cell1(t); ONE grid sync per phase.
#pragma unroll 1
    for (int t = 0; t <= SEQ; ++t) {
        if (t >= 1) {  // ---- layer-2 cell for step t-1 ----
            const __hip_bfloat16* sA = (((t - 1) & 1) ? h1bf1 : h1bf0) + (size_t)brow * DIM;
            const __hip_bfloat16* sB = ((t & 1) ? h2bf1 : h2bf0) + (size_t)brow * DIM;
            run_gemm<false>(sA, sB, breg, lds, tid, w, s, kq, quad, l16, eb0, exr);

            float g4[4] = {0.f, 0.f, 0.f, 0.f};
#pragma unroll
            for (int wv = 0; wv < 8; ++wv)
#pragma unroll
                for (int g = 0; g < 4; ++g) {
                    int n  = (tid & 7) * 4 + g;
                    int dw = (wv * 2048 + n * 64 + erow) ^ ((n & 7) << 2);
                    g4[g] += part[dw];
                }
            float gi = g4[0] + bias[0], gf = g4[1] + bias[1];
            float gg = g4[2] + bias[2], go = g4[3] + bias[3];
            float cn = sigf(gf) * c2f + sigf(gi) * tanhf(gg);
            float hn = sigf(go) * tanhf(cn);
            bool pad = (x[(t - 1) * BATCH + brow] == 0);
            h2f = pad ? hp : hn;             // pad fallback = layer-1 PRE-state
            c2f = pad ? cp : cn;
            st_dev_bf16((((t - 1) & 1) ? h2bf1 : h2bf0) + off, h2f);
        }
        if (t < SEQ) {  // ---- layer-1 cell for step t ----
            int gx = x[t * BATCH + brow];
            const float* sA = emb + (size_t)gx * DIM;   // f32 gather row (own row: erow)
            const __hip_bfloat16* sB = (((t + 1) & 1) ? hbf1 : hbf0) + (size_t)brow * DIM;
            run_gemm<true>(sA, sB, breg, lds, tid, w, s, kq, quad, l16, eb0, exr);

            float g4[4] = {0.f, 0.f, 0.f, 0.f};
#pragma unroll
            for (int wv = 0; wv < 8; ++wv)
#pragma unroll
                for (int g = 0; g < 4; ++g) {
                    int n  = (tid & 7) * 4 + g;
                    int dw = (wv * 2048 + n * 64 + erow) ^ ((n & 7) << 2);
                    g4[g] += part[dw];
                }
            float gi = g4[0] + bias[0], gf = g4[1] + bias[1];
            float gg = g4[2] + bias[2], go = g4[3] + bias[3];
            float cn = sigf(gf) * cc1 + sigf(gi) * tanhf(gg);
            float hn = sigf(go) * tanhf(cn);
            bool pad = (gx == 0);
            float hm = pad ? hc : hn;
            float cm = pad ? cc1 : cn;
            st_dev_bf16(((t & 1) ? h1bf1 : h1bf0) + off, hn);   // UNMASKED h1 -> layer2 input
            st_dev_bf16(((t & 1) ? hbf1 : hbf0) + off, hm);     // masked h -> next cell1
            hp = hc; cp = cc1; hc = hm; cc1 = cm;
            gsync(sync);
        }
    }

    // ---- outputs (f32, [h; c; h2; c2]) ----
    out[0 * BD + off] = hc;
    out[1 * BD + off] = cc1;
    out[2 * BD + off] = h2f;
    out[3 * BD + off] = c2f;
}

__global__ void zero_sync_k(unsigned* sc) {
    if (threadIdx.x == 0) { sc[0] = 0u; sc[64] = 0u; }
}

extern "C" void kernel_launch(void* const* d_in, const int* in_sizes, int n_in,
                              void* d_out, int out_size, void* d_ws, size_t ws_size,
                              hipStream_t stream) {
    (void)in_sizes; (void)n_in; (void)out_size; (void)ws_size;
    const int*   x    = (const int*)d_in[0];
    const float* emb  = (const float*)d_in[1];
    const float* Wih  = (const float*)d_in[2];
    const float* Whh  = (const float*)d_in[3];
    const float* bih  = (const float*)d_in[4];
    const float* bhh  = (const float*)d_in[5];
    const float* h0   = (const float*)d_in[6];
    const float* c0   = (const float*)d_in[7];
    const float* h02  = (const float*)d_in[8];
    const float* c02  = (const float*)d_in[9];

    unsigned* sync = (unsigned*)d_ws;
    __hip_bfloat16* hbase = (__hip_bfloat16*)((char*)d_ws + 1024);
    float* outp = (float*)d_out;

    static int attr_done = 0;
    if (!attr_done) {
        (void)hipFuncSetAttribute((const void*)lstm_persist,
                                  hipFuncAttributeMaxDynamicSharedMemorySize, LDS_BYTES);
        attr_done = 1;
    }

    zero_sync_k<<<1, 64, 0, stream>>>(sync);

    void* args[] = { (void*)&x, (void*)&emb, (void*)&Wih, (void*)&Whh,
                     (void*)&bih, (void*)&bhh, (void*)&h0, (void*)&c0,
                     (void*)&h02, (void*)&c02, (void*)&hbase, (void*)&sync,
                     (void*)&outp };
    hipError_t e = hipLaunchCooperativeKernel((const void*)lstm_persist,
                                              dim3(NBLK), dim3(512), args,
                                              (unsigned)LDS_BYTES, stream);
    if (e != hipSuccess) {
        // Fallback: plain launch. 128 KB LDS forces 1 block/CU and grid==CU
        // count, so all 256 blocks are co-resident and the barrier is safe.
        lstm_persist<<<NBLK, 512, LDS_BYTES, stream>>>(
            x, emb, Wih, Whh, bih, bhh, h0, c0, h02, c02, hbase, sync, outp);
    }
}

// Round 2
// 19658.818 us; speedup vs baseline: 2.1030x; 1.0296x over previous
//
#include <hip/hip_runtime.h>
#include <hip/hip_bf16.h>
#include <stdint.h>

#define SEQ   512
#define BATCH 128
#define DIM   1024
#define BD    (BATCH * DIM)
#define NBLK  256

typedef __bf16 bf16x8 __attribute__((ext_vector_type(8)));
typedef float  f32x4  __attribute__((ext_vector_type(4)));

__device__ __forceinline__ float sigf(float x) { return 1.0f / (1.0f + __expf(-x)); }

__device__ __forceinline__ bf16x8 pack_f32(float4 a, float4 b) {
    bf16x8 r;
    r[0] = (__bf16)a.x; r[1] = (__bf16)a.y; r[2] = (__bf16)a.z; r[3] = (__bf16)a.w;
    r[4] = (__bf16)b.x; r[5] = (__bf16)b.y; r[6] = (__bf16)b.z; r[7] = (__bf16)b.w;
    return r;
}
__device__ __forceinline__ bf16x8 pack_u64(unsigned long long a, unsigned long long b) {
    uint4 u = make_uint4((unsigned)a, (unsigned)(a >> 32), (unsigned)b, (unsigned)(b >> 32));
    return __builtin_bit_cast(bf16x8, u);
}
// Cross-XCD-coherent 8B load / 2B store (per-XCD L2 is not coherent; all
// mutable cross-block state goes through agent-scope atomics -> MALL).
__device__ __forceinline__ unsigned long long ld_dev_u64(const __hip_bfloat16* p) {
    return __hip_atomic_load((const unsigned long long*)p, __ATOMIC_RELAXED,
                             __HIP_MEMORY_SCOPE_AGENT);
}
__device__ __forceinline__ void st_dev_bf16(__hip_bfloat16* p, float v) {
    unsigned short u = __builtin_bit_cast(unsigned short, (__bf16)v);
    __hip_atomic_store((unsigned short*)p, u, __ATOMIC_RELAXED, __HIP_MEMORY_SCOPE_AGENT);
}

// Grid barrier: counter at sc[0], generation at sc[64]. All cross-block data
// moves via agent-scope atomics (already at the coherence point), so no cache
// maintenance is needed here. __syncthreads drains vmcnt -> stores retired.
__device__ __forceinline__ void gsync(unsigned* sc) {
    __syncthreads();
    if (threadIdx.x == 0) {
        unsigned g = __hip_atomic_load(sc + 64, __ATOMIC_RELAXED, __HIP_MEMORY_SCOPE_AGENT);
        unsigned a = __hip_atomic_fetch_add(sc, 1u, __ATOMIC_ACQ_REL, __HIP_MEMORY_SCOPE_AGENT);
        if (a == NBLK - 1) {
            __hip_atomic_store(sc, 0u, __ATOMIC_RELAXED, __HIP_MEMORY_SCOPE_AGENT);
            __hip_atomic_store(sc + 64, g + 1u, __ATOMIC_RELEASE, __HIP_MEMORY_SCOPE_AGENT);
        } else {
            while (__hip_atomic_load(sc + 64, __ATOMIC_ACQUIRE, __HIP_MEMORY_SCOPE_AGENT) == g)
                __builtin_amdgcn_s_sleep(2);
        }
    }
    __syncthreads();
}

// All 16 A-fragment loads issued up-front: one latency exposure per GEMM.
__device__ __forceinline__ void load_h_frags(bf16x8 (&afr)[2][8],
    const __hip_bfloat16* Ab, size_t aoff0, size_t aoff1)
{
#pragma unroll
    for (int kc = 0; kc < 8; ++kc) {
        afr[0][kc] = pack_u64(ld_dev_u64(Ab + aoff0 + kc * 32),
                              ld_dev_u64(Ab + aoff0 + kc * 32 + 4));
        afr[1][kc] = pack_u64(ld_dev_u64(Ab + aoff1 + kc * 32),
                              ld_dev_u64(Ab + aoff1 + kc * 32 + 4));
    }
}
// emb is read-only during the persistent kernel -> plain cacheable loads
// (L2-shared across the 64 col-blocks reading the same gathered rows).
__device__ __forceinline__ void load_emb_frags(bf16x8 (&afr)[2][8],
    const float* e0, const float* e1)
{
#pragma unroll
    for (int kc = 0; kc < 8; ++kc) {
        afr[0][kc] = pack_f32(*(const float4*)(e0 + kc * 32),
                              *(const float4*)(e0 + kc * 32 + 4));
        afr[1][kc] = pack_f32(*(const float4*)(e1 + kc * 32),
                              *(const float4*)(e1 + kc * 32 + 4));
    }
}

__device__ __forceinline__ void mfma_all(const bf16x8 (&afr)[2][8],
    const bf16x8 (&breg)[4][8], f32x4 (&acc)[2][4])
{
#pragma unroll
    for (int kc = 0; kc < 8; ++kc)
#pragma unroll
        for (int mt = 0; mt < 2; ++mt)
#pragma unroll
            for (int nt = 0; nt < 4; ++nt)
                acc[mt][nt] = __builtin_amdgcn_mfma_f32_16x16x32_bf16(
                    afr[mt][kc], breg[nt][kc], acc[mt][nt], 0, 0, 0);
}

// Partials: part[w][n=64][m=32] f32 (64 KB), m-bits XOR-swizzled by n&7 so
// both the b128 writes and the scalar epilogue reads are conflict-free.
__device__ __forceinline__ void write_part(float* part, const f32x4 (&acc)[2][4],
    int w, int quad, int l16)
{
#pragma unroll
    for (int mt = 0; mt < 2; ++mt)
#pragma unroll
        for (int nt = 0; nt < 4; ++nt) {
            int n  = nt * 16 + l16;
            int dw = w * 2048 + n * 32 + ((mt * 16 + quad * 4) ^ ((n & 7) << 2));
            *(f32x4*)(part + dw) = acc[mt][nt];
        }
}
__device__ __forceinline__ void read_part(const float* part, int rr, int jj, float (&g4)[4])
{
    g4[0] = g4[1] = g4[2] = g4[3] = 0.f;
#pragma unroll
    for (int wv = 0; wv < 8; ++wv)
#pragma unroll
        for (int g = 0; g < 4; ++g) {
            int n = jj * 4 + g;
            g4[g] += part[wv * 2048 + n * 32 + (rr ^ ((n & 7) << 2))];
        }
}

// Block = 32 batch rows x 16 hidden cols (r=4, c=64). Wave (s,kq): matrix
// select x K-quarter; weights persist in 128 VGPR/lane; A-frags direct from
// global; zero LDS staging; one grid sync per timestep.
__global__ __launch_bounds__(512, 2) void lstm_persist(
    const int* __restrict__ x, const float* __restrict__ emb,
    const float* __restrict__ Wih, const float* __restrict__ Whh,
    const float* __restrict__ bih, const float* __restrict__ bhh,
    const float* __restrict__ h0, const float* __restrict__ c0,
    const float* __restrict__ h02, const float* __restrict__ c02,
    __hip_bfloat16* __restrict__ hbase, unsigned* __restrict__ sync,
    float* __restrict__ out)
{
    __shared__ float part[8 * 2048];   // 64 KB

    const int tid  = threadIdx.x;
    const int w    = tid >> 6;
    const int lane = tid & 63;
    const int quad = lane >> 4;
    const int l16  = lane & 15;
    const int s    = w & 1;          // 0: @Wih (A = emb | h1), 1: @Whh (A = h | h2)
    const int kq   = w >> 1;         // K-quarter
    const int cg   = blockIdx.x & 63;    // col-tile; bx%8 spreads a row-tile's
    const int mqh  = blockIdx.x >> 6;    // 64 blocks over all 8 XCDs (emb L2 reuse)
    const int R0   = mqh * 32;
    const int J0   = cg * 16;
    const int rr   = tid >> 4;           // epilogue local row 0..31
    const int jj   = tid & 15;           // epilogue local col
    const int col  = J0 + jj;
    const int grow = R0 + rr;
    const size_t off = (size_t)grow * DIM + col;

    const int arow0 = R0 + l16;          // A-frag rows (mt=0 / mt=1)
    const int arow1 = R0 + 16 + l16;
    const int kb    = kq * 256 + quad * 8;
    const size_t aoff0 = (size_t)arow0 * DIM + kb;
    const size_t aoff1 = (size_t)arow1 * DIM + kb;

    __hip_bfloat16* hbf0  = hbase;
    __hip_bfloat16* hbf1  = hbase + BD;
    __hip_bfloat16* h1bf0 = hbase + 2 * BD;
    __hip_bfloat16* h1bf1 = hbase + 3 * BD;
    __hip_bfloat16* h2bf0 = hbase + 4 * BD;
    __hip_bfloat16* h2bf1 = hbase + 5 * BD;

    // ---- persistent weight fragments: W[n = j*4+g][k], direct f32->bf16 ----
    bf16x8 breg[4][8];
    {
        const float* Wm = s ? Whh : Wih;
#pragma unroll
        for (int nt = 0; nt < 4; ++nt) {
            int n = nt * 16 + l16;
            const float* wp = Wm + (size_t)((n & 3) * DIM + J0 + (n >> 2)) * DIM + kb;
#pragma unroll
            for (int kc = 0; kc < 8; ++kc)
                breg[nt][kc] = pack_f32(*(const float4*)(wp + kc * 32),
                                        *(const float4*)(wp + kc * 32 + 4));
        }
    }

    // ---- per-thread persistent cell state (one (row,col) cell/thread) ----
    float hc  = h0[col],  cc1 = c0[col];
    float hp  = hc,       cp  = cc1;     // layer-1 pre-state (pad fallback for cell2)
    float h2f = h02[col], c2f = c02[col];
    float bias[4];
#pragma unroll
    for (int g = 0; g < 4; ++g) bias[g] = bih[g * DIM + col] + bhh[g * DIM + col];

    st_dev_bf16(hbf1 + off, hc);         // parity 1 = "state before step 0"
    st_dev_bf16(h2bf1 + off, h2f);
    gsync(sync);

#pragma unroll 1
    for (int t = 0; t <= SEQ; ++t) {
        bf16x8 afr1[2][8];
        if (t >= 1) {
            // ---- cell2(t-1): s=0 -> h1(t-1)@Wih, s=1 -> h2(t-2)@Whh ----
            {
                const __hip_bfloat16* Ab = (s == 0)
                    ? (((t - 1) & 1) ? h1bf1 : h1bf0)
                    : ((t & 1) ? h2bf1 : h2bf0);
                bf16x8 afr2[2][8];
                load_h_frags(afr2, Ab, aoff0, aoff1);
                f32x4 acc[2][4];
#pragma unroll
                for (int mt = 0; mt < 2; ++mt)
#pragma unroll
                    for (int nt = 0; nt < 4; ++nt) acc[mt][nt] = (f32x4)(0.f);
                mfma_all(afr2, breg, acc);
                write_part(part, acc, w, quad, l16);
            }
            // prefetch cell1(t) operands under cell2's epilogue
            if (t < SEQ) {
                if (s == 0) {
                    int tok0 = x[t * BATCH + arow0];
                    int tok1 = x[t * BATCH + arow1];
                    load_emb_frags(afr1, emb + (size_t)tok0 * DIM + kb,
                                         emb + (size_t)tok1 * DIM + kb);
                } else {
                    load_h_frags(afr1, ((t + 1) & 1) ? hbf1 : hbf0, aoff0, aoff1);
                }
            }
            __syncthreads();
            {   // epilogue cell2(t-1)
                float g4[4]; read_part(part, rr, jj, g4);
                float gi = g4[0] + bias[0], gf = g4[1] + bias[1];
                float gg = g4[2] + bias[2], go = g4[3] + bias[3];
                float cn = sigf(gf) * c2f + sigf(gi) * tanhf(gg);
                float hn = sigf(go) * tanhf(cn);
                bool pad = (x[(t - 1) * BATCH + grow] == 0);
                h2f = pad ? hp : hn;         // pad fallback = layer-1 PRE-state
                c2f = pad ? cp : cn;
                st_dev_bf16((((t - 1) & 1) ? h2bf1 : h2bf0) + off, h2f);
            }
            __syncthreads();                 // partials free for cell1
        } else {
            if (s == 0) {
                int tok0 = x[arow0];
                int tok1 = x[arow1];
                load_emb_frags(afr1, emb + (size_t)tok0 * DIM + kb,
                                     emb + (size_t)tok1 * DIM + kb);
            } else {
                load_h_frags(afr1, hbf1, aoff0, aoff1);
            }
        }
        if (t < SEQ) {
            // ---- cell1(t): s=0 -> emb[x(t)]@Wih, s=1 -> h(t-1)@Whh ----
            f32x4 acc[2][4];
#pragma unroll
            for (int mt = 0; mt < 2; ++mt)
#pragma unroll
                for (int nt = 0; nt < 4; ++nt) acc[mt][nt] = (f32x4)(0.f);
            mfma_all(afr1, breg, acc);
            write_part(part, acc, w, quad, l16);
            __syncthreads();
            {   // epilogue cell1(t)
                float g4[4]; read_part(part, rr, jj, g4);
                int gx = x[t * BATCH + grow];
                float gi = g4[0] + bias[0], gf = g4[1] + bias[1];
                float gg = g4[2] + bias[2], go = g4[3] + bias[3];
                float cn = sigf(gf) * cc1 + sigf(gi) * tanhf(gg);
                float hn = sigf(go) * tanhf(cn);
                bool pad = (gx == 0);
                float hm = pad ? hc : hn;
                float cm = pad ? cc1 : cn;
                st_dev_bf16(((t & 1) ? h1bf1 : h1bf0) + off, hn);  // UNMASKED -> layer2
                st_dev_bf16(((t & 1) ? hbf1 : hbf0) + off, hm);    // masked -> next cell1
                hp = hc; cp = cc1; hc = hm; cc1 = cm;
            }
            gsync(sync);
        }
    }

    out[0 * BD + off] = hc;
    out[1 * BD + off] = cc1;
    out[2 * BD + off] = h2f;
    out[3 * BD + off] = c2f;
}

__global__ void zero_sync_k(unsigned* sc) {
    if (threadIdx.x == 0) { sc[0] = 0u; sc[64] = 0u; }
}

extern "C" void kernel_launch(void* const* d_in, const int* in_sizes, int n_in,
                              void* d_out, int out_size, void* d_ws, size_t ws_size,
                              hipStream_t stream) {
    (void)in_sizes; (void)n_in; (void)out_size; (void)ws_size;
    const int*   x    = (const int*)d_in[0];
    const float* emb  = (const float*)d_in[1];
    const float* Wih  = (const float*)d_in[2];
    const float* Whh  = (const float*)d_in[3];
    const float* bih  = (const float*)d_in[4];
    const float* bhh  = (const float*)d_in[5];
    const float* h0   = (const float*)d_in[6];
    const float* c0   = (const float*)d_in[7];
    const float* h02  = (const float*)d_in[8];
    const float* c02  = (const float*)d_in[9];

    unsigned* sync = (unsigned*)d_ws;
    __hip_bfloat16* hbase = (__hip_bfloat16*)((char*)d_ws + 1024);
    float* outp = (float*)d_out;

    zero_sync_k<<<1, 64, 0, stream>>>(sync);

    void* args[] = { (void*)&x, (void*)&emb, (void*)&Wih, (void*)&Whh,
                     (void*)&bih, (void*)&bhh, (void*)&h0, (void*)&c0,
                     (void*)&h02, (void*)&c02, (void*)&hbase, (void*)&sync,
                     (void*)&outp };
    hipError_t e = hipLaunchCooperativeKernel((const void*)lstm_persist,
                                              dim3(NBLK), dim3(512), args, 0, stream);
    if (e != hipSuccess) {
        // Fallback: plain launch. 64 KB LDS + ~240 VGPR -> 1 block/CU and
        // grid == CU count, so all 256 blocks are co-resident; barrier safe.
        lstm_persist<<<NBLK, 512, 0, stream>>>(
            x, emb, Wih, Whh, bih, bhh, h0, c0, h02, c02, hbase, sync, outp);
    }
}